// Round 5
// baseline (3413.389 us; speedup 1.0000x reference)
//
#include <hip/hip_runtime.h>
#include <cmath>

// ConvLSTM, round 4b: single persistent grid-resident kernel (scope fix).
// Grid 512 blocks (16 tiles x 4 hc-quarters x 8 batch) x 256 thr, 2 blocks/CU.
// Manual grid barrier between timesteps. Cell state in registers across all
// 16 steps. B-fragments direct from L2. A-frags hoisted across ky.
// Register double-buffered z staging. Final NCHW outputs via LDS transpose.

#define CHW  262144            // 64*64*64
#define NBLK 512
#define HBUF 2097152           // elems per h ping-pong buffer (8*CHW)

typedef short bf16x8 __attribute__((ext_vector_type(8)));
typedef float f32x4  __attribute__((ext_vector_type(4)));

static __device__ __forceinline__ ushort f2bf(float f) {
    union { float f; unsigned u; } v; v.f = f;
    unsigned u = v.u;
    return (ushort)((u + 0x7FFFu + ((u >> 16) & 1u)) >> 16);
}
static __device__ __forceinline__ float sigf(float x) {
    return 1.f / (1.f + __expf(-x));
}

// Wt layout: [cq = cix*4+q][tap][g][lane][8j] (ushort).
// element = bf16(Wk[oc = g*64+q*16+(lane&15)][ic = cix*32+(lane>>4)*8+j][ky][kx])
__global__ void transform_w(const float* __restrict__ Wk, ushort* __restrict__ Wt) {
    const int idx  = blockIdx.x * 256 + threadIdx.x;   // 0..36863
    const int lane = idx & 63;
    const int g    = (idx >> 6) & 3;
    const int r2   = idx >> 8;
    const int tap  = r2 % 9;
    const int cq   = r2 / 9;
    const int q    = cq & 3;
    const int cix  = cq >> 2;
    const int oc   = g * 64 + q * 16 + (lane & 15);
    const int icb  = cix * 32 + (lane >> 4) * 8;
    const int ky   = tap / 3, kx = tap - ky * 3;
    ushort* dst = Wt + (size_t)idx * 8;
    #pragma unroll
    for (int j = 0; j < 8; ++j)
        dst[j] = f2bf(Wk[((size_t)(oc * 128 + icb + j) * 3 + ky) * 3 + kx]);
}

__global__ __launch_bounds__(256, 2) void convlstm_all(
    const float*  __restrict__ x,     // (8,16,64,64,64) fp32 NCHW
    const ushort* __restrict__ Wt,    // fragment-ordered bf16 weights
    ushort*       __restrict__ hb,    // 2 ping-pong h buffers, bf16 NHWC
    float*        __restrict__ out,   // d_out: [h fp32 NCHW | c fp32 NCHW]
    unsigned*     __restrict__ bar)   // grid barrier counter (zeroed)
{
    __shared__ __align__(16) ushort zs[324 * 40];     // 25,920 B; unioned w/ buf

    const int tid  = threadIdx.x;
    const int lane = tid & 63;
    const int w    = tid >> 6;
    const int col  = lane & 15;
    const int quad = lane >> 4;
    const int q8   = quad * 8;

    const int tile = blockIdx.x;
    const int ty0  = (tile >> 2) * 16;
    const int tx0  = (tile & 3) * 16;
    const int q    = blockIdx.y;
    const int hc0  = q * 16;
    const int b    = blockIdx.z;

    const int gy_ = ty0 + 4 * w;
    const int gx_ = tx0 + quad * 4;

    const ushort* wq = Wt + (size_t)q * 18432;   // + cix*4*18432

    f32x4 cellv[4];
    f32x4 hv[4];
    #pragma unroll
    for (int r = 0; r < 4; ++r) {
        cellv[r] = (f32x4){0.f, 0.f, 0.f, 0.f};
        hv[r]    = (f32x4){0.f, 0.f, 0.f, 0.f};
    }

    float   px4[11][4];     // x-chunk prefetch
    ushort4 ph[11];         // h-chunk prefetch

    // ---- prefetch chunk 0 of t=0 (x) ----
    {
        const float* xt = x + ((size_t)b * 16 + 0) * CHW;
        #pragma unroll
        for (int k = 0; k < 11; ++k) {
            const int i = tid + k * 256;
            px4[k][0] = px4[k][1] = px4[k][2] = px4[k][3] = 0.f;
            if (i < 2592) {
                const int icq = i / 324;
                const int p   = i - icq * 324;
                const int py  = p / 18;
                const int pxl = p - py * 18;
                const int gy  = ty0 + py - 1;
                const int gx  = tx0 + pxl - 1;
                if (((unsigned)gy < 64u) & ((unsigned)gx < 64u)) {
                    const float* s = xt + (size_t)(icq * 4) * 4096 + gy * 64 + gx;
                    px4[k][0] = s[0];
                    px4[k][1] = s[4096];
                    px4[k][2] = s[8192];
                    px4[k][3] = s[12288];
                }
            }
        }
    }

    for (int t = 0; t < 16; ++t) {
        const ushort* hin = hb + (size_t)(t & 1) * HBUF + (size_t)b * CHW;
        ushort*       ho  = hb + (size_t)((t + 1) & 1) * HBUF + (size_t)b * CHW;
        const float*  xt  = x + ((size_t)b * 16 + t) * CHW;

        f32x4 acc[4][4];
        #pragma unroll
        for (int r = 0; r < 4; ++r)
            #pragma unroll
            for (int g = 0; g < 4; ++g)
                acc[r][g] = (f32x4){0.f, 0.f, 0.f, 0.f};

        #pragma unroll
        for (int cix = 0; cix < 4; ++cix) {
            // ---- drain prefetch regs -> zs ----
            __syncthreads();
            if (cix < 2) {
                #pragma unroll
                for (int k = 0; k < 11; ++k) {
                    const int i = tid + k * 256;
                    if (i < 2592) {
                        const int icq = i / 324;
                        const int p   = i - icq * 324;
                        ushort4 v;
                        v.x = f2bf(px4[k][0]);
                        v.y = f2bf(px4[k][1]);
                        v.z = f2bf(px4[k][2]);
                        v.w = f2bf(px4[k][3]);
                        *(ushort4*)&zs[p * 40 + icq * 4] = v;
                    }
                }
            } else {
                #pragma unroll
                for (int k = 0; k < 11; ++k) {
                    const int i = tid + k * 256;
                    if (i < 2592) {
                        const int p   = i >> 3;
                        const int icq = i & 7;
                        *(ushort4*)&zs[p * 40 + icq * 4] = ph[k];
                    }
                }
            }
            __syncthreads();

            // ---- issue next prefetch (overlaps with compute below) ----
            if (cix < 2) {
                if (cix == 0) {
                    #pragma unroll
                    for (int k = 0; k < 11; ++k) {
                        const int i = tid + k * 256;
                        px4[k][0] = px4[k][1] = px4[k][2] = px4[k][3] = 0.f;
                        if (i < 2592) {
                            const int icq = i / 324;
                            const int p   = i - icq * 324;
                            const int py  = p / 18;
                            const int pxl = p - py * 18;
                            const int gy  = ty0 + py - 1;
                            const int gx  = tx0 + pxl - 1;
                            if (((unsigned)gy < 64u) & ((unsigned)gx < 64u)) {
                                const float* s = xt + (size_t)(32 + icq * 4) * 4096 + gy * 64 + gx;
                                px4[k][0] = s[0];
                                px4[k][1] = s[4096];
                                px4[k][2] = s[8192];
                                px4[k][3] = s[12288];
                            }
                        }
                    }
                } else {
                    #pragma unroll
                    for (int k = 0; k < 11; ++k) {
                        const int i = tid + k * 256;
                        ph[k] = (ushort4){0, 0, 0, 0};
                        if (i < 2592) {
                            const int p   = i >> 3;
                            const int icq = i & 7;
                            const int py  = p / 18;
                            const int pxl = p - py * 18;
                            const int gy  = ty0 + py - 1;
                            const int gx  = tx0 + pxl - 1;
                            if (((unsigned)gy < 64u) & ((unsigned)gx < 64u))
                                ph[k] = *(const ushort4*)&hin[(size_t)(gy * 64 + gx) * 64 + icq * 4];
                        }
                    }
                }
            } else if (cix == 2) {
                #pragma unroll
                for (int k = 0; k < 11; ++k) {
                    const int i = tid + k * 256;
                    ph[k] = (ushort4){0, 0, 0, 0};
                    if (i < 2592) {
                        const int p   = i >> 3;
                        const int icq = i & 7;
                        const int py  = p / 18;
                        const int pxl = p - py * 18;
                        const int gy  = ty0 + py - 1;
                        const int gx  = tx0 + pxl - 1;
                        if (((unsigned)gy < 64u) & ((unsigned)gx < 64u))
                            ph[k] = *(const ushort4*)&hin[(size_t)(gy * 64 + gx) * 64 + 32 + icq * 4];
                    }
                }
            } else if (t < 15) {
                // next: x chunk 0 of step t+1 (independent of h -> crosses barrier)
                const float* xn = xt + CHW;
                #pragma unroll
                for (int k = 0; k < 11; ++k) {
                    const int i = tid + k * 256;
                    px4[k][0] = px4[k][1] = px4[k][2] = px4[k][3] = 0.f;
                    if (i < 2592) {
                        const int icq = i / 324;
                        const int p   = i - icq * 324;
                        const int py  = p / 18;
                        const int pxl = p - py * 18;
                        const int gy  = ty0 + py - 1;
                        const int gx  = tx0 + pxl - 1;
                        if (((unsigned)gy < 64u) & ((unsigned)gx < 64u)) {
                            const float* s = xn + (size_t)(icq * 4) * 4096 + gy * 64 + gx;
                            px4[k][0] = s[0];
                            px4[k][1] = s[4096];
                            px4[k][2] = s[8192];
                            px4[k][3] = s[12288];
                        }
                    }
                }
            }

            // ---- compute: A from LDS (hoisted over ky), B direct from L2 ----
            {
                const ushort* wb = wq + (size_t)cix * 4 * 18432;
                #pragma unroll
                for (int kx = 0; kx < 3; ++kx) {
                    bf16x8 arow[6];
                    #pragma unroll
                    for (int j = 0; j < 6; ++j)
                        arow[j] = *(const bf16x8*)&zs[((4 * w + j) * 18 + col + kx) * 40 + q8];
                    #pragma unroll
                    for (int ky = 0; ky < 3; ++ky) {
                        const int tap = ky * 3 + kx;
                        bf16x8 bfr[4];
                        #pragma unroll
                        for (int g = 0; g < 4; ++g)
                            bfr[g] = *(const bf16x8*)(wb + (size_t)tap * 2048 + g * 512 + lane * 8);
                        #pragma unroll
                        for (int g = 0; g < 4; ++g)
                            #pragma unroll
                            for (int r = 0; r < 4; ++r)
                                acc[r][g] = __builtin_amdgcn_mfma_f32_16x16x32_bf16(
                                    arow[r + ky], bfr[g], acc[r][g], 0, 0, 0);
                    }
                }
            }
        }

        // ---- epilogue: gates + cell update (cell stays in registers) ----
        #pragma unroll
        for (int r = 0; r < 4; ++r) {
            const size_t rowbase = ((size_t)(gy_ + r) * 64 + gx_) * 64 + hc0 + col;
            #pragma unroll
            for (int reg = 0; reg < 4; ++reg) {
                const float ci = acc[r][0][reg];
                const float cf = acc[r][1][reg];
                const float co = acc[r][2][reg];
                const float cg = acc[r][3][reg];
                const float cn = sigf(cf) * cellv[r][reg] + sigf(ci) * tanhf(cg);
                const float hn = sigf(co) * tanhf(cn);
                cellv[r][reg] = cn;
                hv[r][reg]    = hn;
                if (t < 15) ho[rowbase + (size_t)reg * 64] = f2bf(hn);
            }
        }

        // ---- grid barrier (h of step t visible to all before t+1) ----
        if (t < 15) {
            __syncthreads();
            if (tid == 0) {
                __threadfence();
                __hip_atomic_fetch_add(bar, 1u, __ATOMIC_RELEASE, __HIP_MEMORY_SCOPE_AGENT);
                const unsigned target = (unsigned)NBLK * (unsigned)(t + 1);
                while (__hip_atomic_load(bar, __ATOMIC_ACQUIRE, __HIP_MEMORY_SCOPE_AGENT) < target)
                    __builtin_amdgcn_s_sleep(2);
            }
            __syncthreads();
        }
    }

    // ---- final outputs: LDS transpose -> NCHW coalesced stores ----
    float* buf = (float*)zs;                   // [16][257] fp32 = 16,448 B
    __syncthreads();
    #pragma unroll
    for (int pass = 0; pass < 2; ++pass) {
        #pragma unroll
        for (int r = 0; r < 4; ++r)
            #pragma unroll
            for (int reg = 0; reg < 4; ++reg) {
                const int pix = (4 * w + r) * 16 + quad * 4 + reg;
                buf[col * 257 + pix] = pass ? cellv[r][reg] : hv[r][reg];
            }
        __syncthreads();
        float* ob = out + (pass ? 2097152 : 0) + (size_t)b * CHW;
        #pragma unroll
        for (int k = 0; k < 16; ++k) {
            const int item = k * 256 + tid;
            const int chl = item >> 8;
            const int pix = item & 255;
            const int py = pix >> 4, pxl = pix & 15;
            ob[(size_t)(hc0 + chl) * 4096 + (ty0 + py) * 64 + tx0 + pxl] = buf[chl * 257 + pix];
        }
        __syncthreads();
    }
}

extern "C" void kernel_launch(void* const* d_in, const int* in_sizes, int n_in,
                              void* d_out, int out_size, void* d_ws, size_t ws_size,
                              hipStream_t stream) {
    const float* x  = (const float*)d_in[0];
    const float* Wk = (const float*)d_in[1];
    float* out = (float*)d_out;

    ushort*   Wt  = (ushort*)d_ws;                             // 589,824 B
    unsigned* bar = (unsigned*)((char*)d_ws + 589824);
    ushort*   hb  = (ushort*)((char*)d_ws + 1048576);          // 2 x 4,194,304 B

    (void)hipMemsetAsync(bar, 0, 64, stream);
    (void)hipMemsetAsync(hb, 0, 4194304, stream);              // h(-1) = 0
    transform_w<<<144, 256, 0, stream>>>(Wk, Wt);

    dim3 grid(16, 4, 8);
    convlstm_all<<<grid, 256, 0, stream>>>(x, Wt, hb, out, bar);
}

// Round 6
// 2614.111 us; speedup vs baseline: 1.3058x; 1.3058x over previous
//
#include <hip/hip_runtime.h>
#include <cmath>

// ConvLSTM, round 6: persistent kernel with *surgical* cross-XCD coherence.
// - h ping-pong traffic uses relaxed AGENT-scope atomic loads/stores (sc0/sc1,
//   served at L3) -> no acquire/release fences -> L2 stays warm for weights/x.
// - Grid barrier: relaxed fetch_add + relaxed spin (no cache invalidation).
// - No register prefetch arrays (round-5 spill source); direct staging.
// Grid 512 blocks (16 tiles x 4 hc-quarters x 8 batch) x 256 thr, 2 blocks/CU.
// Cell state in registers across all 16 steps. Final NCHW out via LDS transpose.

#define CHW  262144            // 64*64*64
#define NBLK 512
#define HBUF 2097152           // elems per h ping-pong buffer (8*CHW)

typedef short bf16x8 __attribute__((ext_vector_type(8)));
typedef float f32x4  __attribute__((ext_vector_type(4)));

static __device__ __forceinline__ ushort f2bf(float f) {
    union { float f; unsigned u; } v; v.f = f;
    unsigned u = v.u;
    return (ushort)((u + 0x7FFFu + ((u >> 16) & 1u)) >> 16);
}
static __device__ __forceinline__ float sigf(float x) {
    return 1.f / (1.f + __expf(-x));
}
// coherent (L3-visible) 8B load / 2B store for cross-XCD h traffic
static __device__ __forceinline__ ushort4 h_load8(const ushort* p) {
    union { unsigned long long u; ushort4 s; } c;
    c.u = __hip_atomic_load((const unsigned long long*)p,
                            __ATOMIC_RELAXED, __HIP_MEMORY_SCOPE_AGENT);
    return c.s;
}
static __device__ __forceinline__ void h_store2(ushort* p, ushort v) {
    __hip_atomic_store(p, v, __ATOMIC_RELAXED, __HIP_MEMORY_SCOPE_AGENT);
}

// Wt layout: [cq = cix*4+q][tap][g][lane][8j] (ushort).
// element = bf16(Wk[oc = g*64+q*16+(lane&15)][ic = cix*32+(lane>>4)*8+j][ky][kx])
__global__ void transform_w(const float* __restrict__ Wk, ushort* __restrict__ Wt) {
    const int idx  = blockIdx.x * 256 + threadIdx.x;   // 0..36863
    const int lane = idx & 63;
    const int g    = (idx >> 6) & 3;
    const int r2   = idx >> 8;
    const int tap  = r2 % 9;
    const int cq   = r2 / 9;
    const int q    = cq & 3;
    const int cix  = cq >> 2;
    const int oc   = g * 64 + q * 16 + (lane & 15);
    const int icb  = cix * 32 + (lane >> 4) * 8;
    const int ky   = tap / 3, kx = tap - ky * 3;
    ushort* dst = Wt + (size_t)idx * 8;
    #pragma unroll
    for (int j = 0; j < 8; ++j)
        dst[j] = f2bf(Wk[((size_t)(oc * 128 + icb + j) * 3 + ky) * 3 + kx]);
}

__global__ __launch_bounds__(256, 2) void convlstm_all(
    const float*  __restrict__ x,     // (8,16,64,64,64) fp32 NCHW
    const ushort* __restrict__ Wt,    // fragment-ordered bf16 weights
    ushort*       __restrict__ hb,    // 2 ping-pong h buffers, bf16 NHWC
    float*        __restrict__ out,   // d_out: [h fp32 NCHW | c fp32 NCHW]
    unsigned*     __restrict__ bar)   // grid barrier counter (zeroed)
{
    __shared__ __align__(16) ushort zs[324 * 40];     // 25,920 B; reused as buf

    const int tid  = threadIdx.x;
    const int lane = tid & 63;
    const int w    = tid >> 6;
    const int col  = lane & 15;
    const int quad = lane >> 4;
    const int q8   = quad * 8;

    const int tile = blockIdx.x;
    const int ty0  = (tile >> 2) * 16;
    const int tx0  = (tile & 3) * 16;
    const int q    = blockIdx.y;
    const int hc0  = q * 16;
    const int b    = blockIdx.z;

    const int gy_ = ty0 + 4 * w;
    const int gx_ = tx0 + quad * 4;

    const ushort* wq = Wt + (size_t)q * 18432;   // + cix*4*18432

    f32x4 cellv[4];
    f32x4 hv[4];
    #pragma unroll
    for (int r = 0; r < 4; ++r) {
        cellv[r] = (f32x4){0.f, 0.f, 0.f, 0.f};
        hv[r]    = (f32x4){0.f, 0.f, 0.f, 0.f};
    }

    for (int t = 0; t < 16; ++t) {
        const ushort* hin = hb + (size_t)(t & 1) * HBUF + (size_t)b * CHW;
        ushort*       ho  = hb + (size_t)((t + 1) & 1) * HBUF + (size_t)b * CHW;
        const float*  xt  = x + ((size_t)b * 16 + t) * CHW;

        f32x4 acc[4][4];
        #pragma unroll
        for (int r = 0; r < 4; ++r)
            #pragma unroll
            for (int g = 0; g < 4; ++g)
                acc[r][g] = (f32x4){0.f, 0.f, 0.f, 0.f};

        #pragma unroll
        for (int cix = 0; cix < 4; ++cix) {
            __syncthreads();   // zs free from previous chunk's reads
            if (cix < 2) {
                // x: NCHW fp32, 4 plane loads + cvt per item
                #pragma unroll
                for (int k = 0; k < 11; ++k) {
                    const int i = tid + k * 256;
                    if (i < 2592) {
                        const int icq = i / 324;
                        const int p   = i - icq * 324;
                        const int py  = p / 18;
                        const int pxl = p - py * 18;
                        const int gy  = ty0 + py - 1;
                        const int gx  = tx0 + pxl - 1;
                        ushort4 v = {0, 0, 0, 0};
                        if (((unsigned)gy < 64u) & ((unsigned)gx < 64u)) {
                            const float* s = xt + (size_t)(cix * 32 + icq * 4) * 4096
                                                + gy * 64 + gx;
                            v.x = f2bf(s[0]);
                            v.y = f2bf(s[4096]);
                            v.z = f2bf(s[8192]);
                            v.w = f2bf(s[12288]);
                        }
                        *(ushort4*)&zs[p * 40 + icq * 4] = v;
                    }
                }
            } else {
                // h: NHWC bf16, one coherent 8B load per item
                #pragma unroll
                for (int k = 0; k < 11; ++k) {
                    const int i = tid + k * 256;
                    if (i < 2592) {
                        const int p   = i >> 3;
                        const int icq = i & 7;
                        const int py  = p / 18;
                        const int pxl = p - py * 18;
                        const int gy  = ty0 + py - 1;
                        const int gx  = tx0 + pxl - 1;
                        ushort4 v = {0, 0, 0, 0};
                        if (((unsigned)gy < 64u) & ((unsigned)gx < 64u))
                            v = h_load8(&hin[(size_t)(gy * 64 + gx) * 64
                                             + (cix - 2) * 32 + icq * 4]);
                        *(ushort4*)&zs[p * 40 + icq * 4] = v;
                    }
                }
            }
            __syncthreads();

            // ---- compute: A from LDS (hoisted over ky), B from warm L1/L2 ----
            {
                const ushort* wb = wq + (size_t)cix * 4 * 18432;
                #pragma unroll
                for (int kx = 0; kx < 3; ++kx) {
                    bf16x8 arow[6];
                    #pragma unroll
                    for (int j = 0; j < 6; ++j)
                        arow[j] = *(const bf16x8*)&zs[((4 * w + j) * 18 + col + kx) * 40 + q8];
                    #pragma unroll
                    for (int ky = 0; ky < 3; ++ky) {
                        const int tap = ky * 3 + kx;
                        bf16x8 bfr[4];
                        #pragma unroll
                        for (int g = 0; g < 4; ++g)
                            bfr[g] = *(const bf16x8*)(wb + (size_t)tap * 2048 + g * 512 + lane * 8);
                        #pragma unroll
                        for (int g = 0; g < 4; ++g)
                            #pragma unroll
                            for (int r = 0; r < 4; ++r)
                                acc[r][g] = __builtin_amdgcn_mfma_f32_16x16x32_bf16(
                                    arow[r + ky], bfr[g], acc[r][g], 0, 0, 0);
                    }
                }
            }
        }

        // ---- epilogue: gates + cell update (cell stays in registers) ----
        #pragma unroll
        for (int r = 0; r < 4; ++r) {
            const size_t rowbase = ((size_t)(gy_ + r) * 64 + gx_) * 64 + hc0 + col;
            #pragma unroll
            for (int reg = 0; reg < 4; ++reg) {
                const float ci = acc[r][0][reg];
                const float cf = acc[r][1][reg];
                const float co = acc[r][2][reg];
                const float cg = acc[r][3][reg];
                const float cn = sigf(cf) * cellv[r][reg] + sigf(ci) * tanhf(cg);
                const float hn = sigf(co) * tanhf(cn);
                cellv[r][reg] = cn;
                hv[r][reg]    = hn;
                if (t < 15)
                    h_store2(&ho[rowbase + (size_t)reg * 64], f2bf(hn));  // coherent
            }
        }

        // ---- grid barrier: relaxed atomics only (no L2 invalidation) ----
        if (t < 15) {
            __syncthreads();   // drains vmcnt(0) for all waves -> h at L3
            if (tid == 0) {
                asm volatile("s_waitcnt vmcnt(0)" ::: "memory");
                __hip_atomic_fetch_add(bar, 1u, __ATOMIC_RELAXED,
                                       __HIP_MEMORY_SCOPE_AGENT);
                const unsigned target = (unsigned)NBLK * (unsigned)(t + 1);
                while (__hip_atomic_load(bar, __ATOMIC_RELAXED,
                                         __HIP_MEMORY_SCOPE_AGENT) < target)
                    __builtin_amdgcn_s_sleep(4);
            }
            __syncthreads();
        }
    }

    // ---- final outputs: LDS transpose -> NCHW coalesced stores ----
    float* buf = (float*)zs;                   // [16][257] fp32 = 16,448 B
    __syncthreads();
    #pragma unroll
    for (int pass = 0; pass < 2; ++pass) {
        #pragma unroll
        for (int r = 0; r < 4; ++r)
            #pragma unroll
            for (int reg = 0; reg < 4; ++reg) {
                const int pix = (4 * w + r) * 16 + quad * 4 + reg;
                buf[col * 257 + pix] = pass ? cellv[r][reg] : hv[r][reg];
            }
        __syncthreads();
        float* ob = out + (pass ? 2097152 : 0) + (size_t)b * CHW;
        #pragma unroll
        for (int k = 0; k < 16; ++k) {
            const int item = k * 256 + tid;
            const int chl = item >> 8;
            const int pix = item & 255;
            const int py = pix >> 4, pxl = pix & 15;
            ob[(size_t)(hc0 + chl) * 4096 + (ty0 + py) * 64 + tx0 + pxl] = buf[chl * 257 + pix];
        }
        __syncthreads();
    }
}

extern "C" void kernel_launch(void* const* d_in, const int* in_sizes, int n_in,
                              void* d_out, int out_size, void* d_ws, size_t ws_size,
                              hipStream_t stream) {
    const float* x  = (const float*)d_in[0];
    const float* Wk = (const float*)d_in[1];
    float* out = (float*)d_out;

    ushort*   Wt  = (ushort*)d_ws;                             // 589,824 B
    unsigned* bar = (unsigned*)((char*)d_ws + 589824);
    ushort*   hb  = (ushort*)((char*)d_ws + 1048576);          // 2 x 4,194,304 B

    (void)hipMemsetAsync(bar, 0, 64, stream);
    (void)hipMemsetAsync(hb, 0, 4194304, stream);              // h(-1) = 0
    transform_w<<<144, 256, 0, stream>>>(Wk, Wt);

    dim3 grid(16, 4, 8);
    convlstm_all<<<grid, 256, 0, stream>>>(x, Wt, hb, out, bar);
}

// Round 7
// 713.470 us; speedup vs baseline: 4.7842x; 3.6639x over previous
//
#include <hip/hip_runtime.h>
#include <cmath>

// ConvLSTM round 7: back to 16-launch structure (free inter-step coherence),
// + x pre-converted to bf16 NHWC once, + LDS double-buffered z staging
// (stage chunk c+1 overlapped with chunk c MFMAs), 1 barrier per chunk.
// Step grid: 512 blocks (16 tiles x 4 hc-quarters x 8 batch) x 256 thr.

#define CHW 262144             // 64*64*64
#define ZSZ 12960              // ushorts per z buffer (324*40)

typedef short bf16x8 __attribute__((ext_vector_type(8)));
typedef float f32x4  __attribute__((ext_vector_type(4)));

static __device__ __forceinline__ ushort f2bf(float f) {
    union { float f; unsigned u; } v; v.f = f;
    unsigned u = v.u;
    return (ushort)((u + 0x7FFFu + ((u >> 16) & 1u)) >> 16);
}
static __device__ __forceinline__ float bf2f(ushort u) {
    union { unsigned u; float f; } v; v.u = (unsigned)u << 16; return v.f;
}
static __device__ __forceinline__ float sigf(float x) {
    return 1.f / (1.f + __expf(-x));
}

// Wt layout: [cq = cix*4+q][tap][g][lane][8j] (ushort).
// element = bf16(Wk[oc = g*64+q*16+(lane&15)][ic = cix*32+(lane>>4)*8+j][ky][kx])
__global__ void transform_w(const float* __restrict__ Wk, ushort* __restrict__ Wt) {
    const int idx  = blockIdx.x * 256 + threadIdx.x;   // 0..36863
    const int lane = idx & 63;
    const int g    = (idx >> 6) & 3;
    const int r2   = idx >> 8;
    const int tap  = r2 % 9;
    const int cq   = r2 / 9;
    const int q    = cq & 3;
    const int cix  = cq >> 2;
    const int oc   = g * 64 + q * 16 + (lane & 15);
    const int icb  = cix * 32 + (lane >> 4) * 8;
    const int ky   = tap / 3, kx = tap - ky * 3;
    ushort* dst = Wt + (size_t)idx * 8;
    #pragma unroll
    for (int j = 0; j < 8; ++j)
        dst[j] = f2bf(Wk[((size_t)(oc * 128 + icb + j) * 3 + ky) * 3 + kx]);
}

// x (8,16,64,64,64) fp32 NCHW -> xb (8,16,4096,64) bf16 NHWC (per bt volume)
__global__ __launch_bounds__(256) void xconv(const float* __restrict__ x,
                                             ushort* __restrict__ xb) {
    __shared__ ushort T[256 * 66];
    const int tid = threadIdx.x;
    const int pg  = blockIdx.x;        // 16 pixel-groups of 256
    const int bt  = blockIdx.y;        // 128
    const float* xt = x  + (size_t)bt * CHW;
    ushort*      xo = xb + (size_t)bt * CHW;
    const int p0 = pg * 256;
    #pragma unroll
    for (int ch = 0; ch < 64; ++ch)
        T[tid * 66 + ch] = f2bf(xt[(size_t)ch * 4096 + p0 + tid]);
    __syncthreads();
    #pragma unroll
    for (int k = 0; k < 64; ++k) {
        const int item = k * 256 + tid;
        const int px = item >> 6, ch = item & 63;
        xo[(size_t)(p0 + px) * 64 + ch] = T[px * 66 + ch];
    }
}

// stage one 32-channel haloed 18x18 chunk from NHWC bf16 src into LDS buffer
static __device__ __forceinline__ void stage_chunk(
    ushort* __restrict__ dst, const ushort* __restrict__ src,
    int tid, int ty0, int tx0) {
    #pragma unroll
    for (int k = 0; k < 11; ++k) {
        const int i = tid + k * 256;
        if (i < 2592) {
            const int p   = i >> 3;
            const int icq = i & 7;
            const int py  = p / 18;
            const int pxl = p - py * 18;
            const int gy  = ty0 + py - 1;
            const int gx  = tx0 + pxl - 1;
            ushort4 v = {0, 0, 0, 0};
            if (((unsigned)gy < 64u) & ((unsigned)gx < 64u))
                v = *(const ushort4*)&src[(size_t)(gy * 64 + gx) * 64 + icq * 4];
            *(ushort4*)&dst[p * 40 + icq * 4] = v;
        }
    }
}

__global__ __launch_bounds__(256) void convlstm_step(
    const ushort* __restrict__ xb,    // (8,16,4096,64) bf16 NHWC
    const ushort* __restrict__ Wt,    // fragment-ordered bf16 weights
    const ushort* __restrict__ hin,   // (8,4096,64) bf16 NHWC
    ushort*       __restrict__ hout,  // (8,4096,64) bf16 NHWC
    float*        __restrict__ cell,  // (8,4096,64) fp32 NHWC, in-place
    int t, int first)
{
    __shared__ __align__(16) ushort zs[2 * ZSZ];      // 51,840 B double buffer

    const int tid  = threadIdx.x;
    const int lane = tid & 63;
    const int w    = tid >> 6;
    const int col  = lane & 15;
    const int quad = lane >> 4;
    const int q8   = quad * 8;

    const int tile = blockIdx.x;
    const int ty0  = (tile >> 2) * 16;
    const int tx0  = (tile & 3) * 16;
    const int q    = blockIdx.y;
    const int hc0  = q * 16;
    const int b    = blockIdx.z;

    const ushort* xt = xb + ((size_t)b * 16 + t) * CHW;
    const ushort* hb = hin + (size_t)b * CHW;
    float*        cb = cell + (size_t)b * CHW;
    ushort*       ho = hout + (size_t)b * CHW;

    const int gy_ = ty0 + 4 * w;
    const int gx_ = tx0 + quad * 4;

    const ushort* wq = Wt + (size_t)q * 18432;

    // prefetch previous cell (acc layout); latency hides under K loop
    f32x4 cpv[4];
    #pragma unroll
    for (int r = 0; r < 4; ++r)
        #pragma unroll
        for (int reg = 0; reg < 4; ++reg)
            cpv[r][reg] = first ? 0.f
                : cb[((size_t)(gy_ + r) * 64 + gx_ + reg) * 64 + hc0 + col];

    f32x4 acc[4][4];
    #pragma unroll
    for (int r = 0; r < 4; ++r)
        #pragma unroll
        for (int g = 0; g < 4; ++g)
            acc[r][g] = (f32x4){0.f, 0.f, 0.f, 0.f};

    // chunk sources: 0,1 -> x channels 0-31/32-63; 2,3 -> h channels 0-31/32-63
    stage_chunk(zs, xt, tid, ty0, tx0);
    __syncthreads();

    #pragma unroll
    for (int cix = 0; cix < 4; ++cix) {
        ushort* cur = zs + (cix & 1) * ZSZ;
        ushort* nxt = zs + ((cix + 1) & 1) * ZSZ;

        // stage next chunk into the idle buffer (no barrier: nxt unread this iter);
        // compiler interleaves these loads/stores with the MFMAs below.
        if (cix == 0) stage_chunk(nxt, xt + 32, tid, ty0, tx0);
        else if (cix == 1) stage_chunk(nxt, hb, tid, ty0, tx0);
        else if (cix == 2) stage_chunk(nxt, hb + 32, tid, ty0, tx0);

        // compute: A from LDS (hoisted over ky), B direct from warm L1/L2
        const ushort* wb = wq + (size_t)cix * 4 * 18432;
        #pragma unroll
        for (int kx = 0; kx < 3; ++kx) {
            bf16x8 arow[6];
            #pragma unroll
            for (int j = 0; j < 6; ++j)
                arow[j] = *(const bf16x8*)&cur[((4 * w + j) * 18 + col + kx) * 40 + q8];
            #pragma unroll
            for (int ky = 0; ky < 3; ++ky) {
                const int tap = ky * 3 + kx;
                bf16x8 bfr[4];
                #pragma unroll
                for (int g = 0; g < 4; ++g)
                    bfr[g] = *(const bf16x8*)(wb + (size_t)tap * 2048 + g * 512 + lane * 8);
                #pragma unroll
                for (int g = 0; g < 4; ++g)
                    #pragma unroll
                    for (int r = 0; r < 4; ++r)
                        acc[r][g] = __builtin_amdgcn_mfma_f32_16x16x32_bf16(
                            arow[r + ky], bfr[g], acc[r][g], 0, 0, 0);
            }
        }
        __syncthreads();   // nxt fully written & cur fully read before roles swap
    }

    // epilogue: gates + state update, direct NHWC coalesced stores
    #pragma unroll
    for (int r = 0; r < 4; ++r) {
        const size_t rowbase = ((size_t)(gy_ + r) * 64 + gx_) * 64 + hc0 + col;
        #pragma unroll
        for (int reg = 0; reg < 4; ++reg) {
            const float ci = acc[r][0][reg];
            const float cf = acc[r][1][reg];
            const float co = acc[r][2][reg];
            const float cg = acc[r][3][reg];
            const float cn = sigf(cf) * cpv[r][reg] + sigf(ci) * tanhf(cg);
            const float hn = sigf(co) * tanhf(cn);
            cb[rowbase + (size_t)reg * 64] = cn;
            ho[rowbase + (size_t)reg * 64] = f2bf(hn);
        }
    }
}

// NHWC -> NCHW final outputs: d_out = [h fp32 | c fp32], each (8,64,4096)
__global__ __launch_bounds__(256) void conv_out(
    const ushort* __restrict__ hN, const float* __restrict__ cN,
    float* __restrict__ out)
{
    __shared__ float T[64][65];
    const int tid  = threadIdx.x;
    const int pg   = blockIdx.x;        // 64 pixel-groups of 64
    const int b    = blockIdx.y;
    const int tsel = blockIdx.z;        // 0 = h, 1 = c
    const int pix0 = pg * 64;

    #pragma unroll
    for (int k = 0; k < 16; ++k) {
        const int idx = k * 256 + tid;
        const int pl = idx >> 6, ch = idx & 63;
        const size_t src = (size_t)b * CHW + (size_t)(pix0 + pl) * 64 + ch;
        T[pl][ch] = tsel ? cN[src] : bf2f(hN[src]);
    }
    __syncthreads();
    float* base = out + (tsel ? 2097152 : 0);
    #pragma unroll
    for (int k = 0; k < 16; ++k) {
        const int idx = k * 256 + tid;
        const int ch = idx >> 6, pl = idx & 63;
        base[(size_t)b * CHW + (size_t)ch * 4096 + pix0 + pl] = T[pl][ch];
    }
}

extern "C" void kernel_launch(void* const* d_in, const int* in_sizes, int n_in,
                              void* d_out, int out_size, void* d_ws, size_t ws_size,
                              hipStream_t stream) {
    const float* x  = (const float*)d_in[0];
    const float* Wk = (const float*)d_in[1];
    float* out = (float*)d_out;

    char* ws = (char*)d_ws;
    ushort* Wt   = (ushort*)ws;                        // 589,824 B @ 0
    float*  cb   = (float*)(ws + (1u << 20));          // 8,388,608 B @ 1 MB
    ushort* hb0  = (ushort*)(ws + (16u << 20));        // 4,194,304 B @ 16 MB
    ushort* hb1  = (ushort*)(ws + (20u << 20));        // 4,194,304 B @ 20 MB
    ushort* xb   = (ushort*)(ws + (32u << 20));        // 67,108,864 B @ 32 MB

    (void)hipMemsetAsync(hb0, 0, 4194304, stream);     // h(-1) = 0
    transform_w<<<144, 256, 0, stream>>>(Wk, Wt);
    xconv<<<dim3(16, 128), 256, 0, stream>>>(x, xb);

    dim3 grid(16, 4, 8);
    for (int t = 0; t < 16; ++t) {
        const ushort* hi = (t & 1) ? hb1 : hb0;
        ushort*       ho = (t & 1) ? hb0 : hb1;
        convlstm_step<<<grid, 256, 0, stream>>>(xb, Wt, hi, ho, cb, t, t == 0);
    }
    // t=15 wrote hb0
    conv_out<<<dim3(64, 8, 2), 256, 0, stream>>>(hb0, cb, out);
}